// Round 1
// baseline (39569.235 us; speedup 1.0000x reference)
//
#include <hip/hip_runtime.h>
#include <cstdint>

#define B_SZ 8192
#define T_SZ 2048
#define HDIM 64

// ---- model constants (folded to fp32 literals, full double precision) ----
#define C_L0        0.089f
#define C_LTS       0.126f
#define C_LMIN      (0.5f * 0.089f)
#define C_LMAX      (1.6f * 0.089f)
#define C_KT        35.0f
#define C_CT        0.2f
#define C_VMAX_L0   (10.0f * 0.089f)
#define C_AF_INV    4.0f                   // 1/AF, AF=0.25
#define C_FAT_RATE  0.01f
#define C_REC_RATE  0.002f
#define C_TAU_ACT   0.01f
#define C_TAU_DEACT 0.04f
#define C_L0SIN     0.0077598346f          // L0 * sin(0.0873)
#define C_LMT_DEF   0.2146610680f          // LTS + L0*cos(0.0873)
#define C_INV_EM5   0.006783655f           // 1/(e^5 - 1)
#define C_INV_LTS   (1.0f / 0.126f)
#define C_INV_L0    (1.0f / 0.089f)
#define C_NN_SCALE  0.02f                  // (1-PHYSICS_WEIGHT) * 0.1

__device__ __forceinline__ float fast_tanh(float x) {
    float e2 = __expf(2.0f * x);
    return (e2 - 1.0f) / (e2 + 1.0f);
}

__device__ __forceinline__ float clampf(float x, float lo, float hi) {
    return fminf(fmaxf(x, lo), hi);
}

__global__ __launch_bounds__(256) void ode_kernel(
    const float* __restrict__ init_state,   // (B,3)
    const float* __restrict__ exc,          // (B,T)
    const float* __restrict__ tspan,        // (T,)
    const float* __restrict__ W1,           // (4,64)
    const float* __restrict__ b1,           // (64,)
    const float* __restrict__ W2,           // (64,64)
    const float* __restrict__ b2,           // (64,)
    const float* __restrict__ W3,           // (64,3)
    const float* __restrict__ b3,           // (3,)
    float* __restrict__ out)                // (T,B,3)
{
    const int tid = threadIdx.x;
    const int eg  = tid & 63;                                   // element within block
    const int hg  = __builtin_amdgcn_readfirstlane(tid >> 6);   // wave index -> h-group (scalar)
    const int h0  = hg << 4;                                    // 16 hidden cols per thread
    const int e_global = (blockIdx.x << 6) + eg;

    __shared__ float H1[HDIM * 64];   // [j][eg] : stride-1 in eg -> conflict-free
    __shared__ float YS[3][64];       // current eval-stage state (raw, unclipped)
    __shared__ float P[4][3][64];     // layer-3 partials per h-group

    // --- init: wave 0 owns the RK4 state registers ---
    float yb0 = 0.f, yb1 = 0.f, yb2 = 0.f;    // y at step start (valid on hg==0)
    float ka0 = 0.f, ka1 = 0.f, ka2 = 0.f;    // k1 + 2k2 + 2k3 accumulator
    if (hg == 0) {
        yb0 = init_state[e_global * 3 + 0];
        yb1 = init_state[e_global * 3 + 1];
        yb2 = init_state[e_global * 3 + 2];
        YS[0][eg] = yb0; YS[1][eg] = yb1; YS[2][eg] = yb2;
        // out[0] = initial state
        out[(size_t)e_global * 3 + 0] = yb0;
        out[(size_t)e_global * 3 + 1] = yb1;
        out[(size_t)e_global * 3 + 2] = yb2;
    }
    __syncthreads();

    // excitation column for k1 of step i is col max(i-1,0); for k2..k4 it's col i.
    float excA = exc[(size_t)e_global * T_SZ + 0];   // k1 column (step 0: col 0)
    float t0 = tspan[0];

    for (int i = 0; i < T_SZ - 1; ++i) {
        const float t1 = tspan[i + 1];
        const float dt = t1 - t0;
        const float excB = exc[(size_t)e_global * T_SZ + i];   // k2..k4 column

        #pragma unroll 1
        for (int ev = 0; ev < 4; ++ev) {
            const float excv = (ev == 0) ? excA : excB;

            // raw state for this stage (NN uses raw; physics clips internally)
            const float s0 = YS[0][eg];
            const float s1 = YS[1][eg];
            const float s2 = YS[2][eg];

            // ---- layer 1: h1[h] = tanh(x @ W1 + b1), write [j][eg] ----
            #pragma unroll
            for (int n = 0; n < 16; ++n) {
                const int h = h0 + n;
                float pre = b1[h];
                pre = fmaf(s0,   W1[h],        pre);
                pre = fmaf(s1,   W1[64  + h],  pre);
                pre = fmaf(s2,   W1[128 + h],  pre);
                pre = fmaf(excv, W1[192 + h],  pre);
                H1[h * 64 + eg] = fast_tanh(pre);
            }
            __syncthreads();

            // ---- layer 2: acc[n] = b2 + sum_j h1[j] * W2[j][h0+n] ----
            float acc[16];
            #pragma unroll
            for (int n = 0; n < 16; ++n) acc[n] = b2[h0 + n];
            #pragma unroll 4
            for (int j = 0; j < 64; ++j) {
                const float a = H1[j * 64 + eg];          // ds_read_b32, stride-1
                const float* __restrict__ w2row = W2 + j * 64 + h0;  // wave-uniform -> s_load
                #pragma unroll
                for (int n = 0; n < 16; ++n)
                    acc[n] = fmaf(a, w2row[n], acc[n]);
            }

            // ---- layer 3 partials ----
            float p0 = 0.f, p1 = 0.f, p2 = 0.f;
            #pragma unroll
            for (int n = 0; n < 16; ++n) {
                const float h2 = fast_tanh(acc[n]);
                const int h = h0 + n;
                p0 = fmaf(h2, W3[h * 3 + 0], p0);
                p1 = fmaf(h2, W3[h * 3 + 1], p1);
                p2 = fmaf(h2, W3[h * 3 + 2], p2);
            }
            P[hg][0][eg] = p0; P[hg][1][eg] = p1; P[hg][2][eg] = p2;
            __syncthreads();

            // ---- wave 0: combine + physics + RK4 bookkeeping ----
            if (hg == 0) {
                const float nn0 = C_NN_SCALE * fast_tanh(P[0][0][eg] + P[1][0][eg] + P[2][0][eg] + P[3][0][eg] + b3[0]);
                const float nn1 = C_NN_SCALE * fast_tanh(P[0][1][eg] + P[1][1][eg] + P[2][1][eg] + P[3][1][eg] + b3[1]);
                const float nn2 = C_NN_SCALE * fast_tanh(P[0][2][eg] + P[1][2][eg] + P[2][2][eg] + P[3][2][eg] + b3[2]);

                // physics_rhs on clipped state
                const float lM  = clampf(s0, C_LMIN, C_LMAX);
                const float act = clampf(s1, 0.01f, 1.0f);
                const float fat = clampf(s2, 0.0f, 1.0f);
                const float a_eff = act * (1.0f - fat);
                float sin_p = clampf(C_L0SIN / lM, 0.0f, 0.99f);
                const float cos_p = sqrtf(1.0f - sin_p * sin_p);
                const float lT   = C_LMT_DEF - lM * cos_p;
                const float epsT = (lT - C_LTS) * C_INV_LTS;
                const float fT   = (epsT > 0.0f) ? C_CT * (__expf(C_KT * epsT) - 1.0f) : 0.0f;
                const float lN   = lM * C_INV_L0;
                const float d1   = lN - 1.0f;
                const float fL   = __expf(-d1 * d1 * (1.0f / 0.45f));
                const float fPE  = (lN > 1.0f) ? (__expf(8.3333333333f * d1) - 1.0f) * C_INV_EM5 : 0.0f;
                const float fV   = (fT / cos_p - fPE) / (a_eff * fL + 0.001f);
                float vN = (fV - 1.0f) / (1.0f + fabsf(fV) * C_AF_INV);
                vN = clampf(vN, -1.0f, 1.5f);
                const float r0 = C_VMAX_L0 * vN + nn0;
                const float tau = (excv > act) ? C_TAU_ACT * (0.5f + 1.5f * act)
                                               : C_TAU_DEACT / (0.5f + 1.5f * act);
                const float r1 = (excv - act) / tau + nn1;
                const float r2 = C_FAT_RATE * a_eff * (1.0f - fat)
                               - C_REC_RATE * (1.0f - a_eff) * fat + nn2;

                float st0, st1, st2;
                if (ev == 0) {
                    ka0 = r0; ka1 = r1; ka2 = r2;
                    st0 = fmaf(0.5f * dt, r0, yb0); st1 = fmaf(0.5f * dt, r1, yb1); st2 = fmaf(0.5f * dt, r2, yb2);
                } else if (ev == 1) {
                    ka0 = fmaf(2.0f, r0, ka0); ka1 = fmaf(2.0f, r1, ka1); ka2 = fmaf(2.0f, r2, ka2);
                    st0 = fmaf(0.5f * dt, r0, yb0); st1 = fmaf(0.5f * dt, r1, yb1); st2 = fmaf(0.5f * dt, r2, yb2);
                } else if (ev == 2) {
                    ka0 = fmaf(2.0f, r0, ka0); ka1 = fmaf(2.0f, r1, ka1); ka2 = fmaf(2.0f, r2, ka2);
                    st0 = fmaf(dt, r0, yb0); st1 = fmaf(dt, r1, yb1); st2 = fmaf(dt, r2, yb2);
                } else {
                    const float c = dt * (1.0f / 6.0f);
                    yb0 = fmaf(c, ka0 + r0, yb0);
                    yb1 = fmaf(c, ka1 + r1, yb1);
                    yb2 = fmaf(c, ka2 + r2, yb2);
                    st0 = yb0; st1 = yb1; st2 = yb2;
                    const size_t ob = (size_t)(i + 1) * (B_SZ * 3) + (size_t)e_global * 3;
                    out[ob + 0] = yb0; out[ob + 1] = yb1; out[ob + 2] = yb2;
                }
                YS[0][eg] = st0; YS[1][eg] = st1; YS[2][eg] = st2;
            }
            __syncthreads();
        }

        excA = excB;   // col i becomes k1's column for step i+1
        t0 = t1;
    }
}

extern "C" void kernel_launch(void* const* d_in, const int* in_sizes, int n_in,
                              void* d_out, int out_size, void* d_ws, size_t ws_size,
                              hipStream_t stream) {
    const float* init  = (const float*)d_in[0];
    const float* exc   = (const float*)d_in[1];
    const float* tspan = (const float*)d_in[2];
    const float* W1    = (const float*)d_in[3];
    const float* b1    = (const float*)d_in[4];
    const float* W2    = (const float*)d_in[5];
    const float* b2    = (const float*)d_in[6];
    const float* W3    = (const float*)d_in[7];
    const float* b3    = (const float*)d_in[8];

    hipLaunchKernelGGL(ode_kernel, dim3(B_SZ / 64), dim3(256), 0, stream,
                       init, exc, tspan, W1, b1, W2, b2, W3, b3, (float*)d_out);
}

// Round 2
// 28651.627 us; speedup vs baseline: 1.3810x; 1.3810x over previous
//
#include <hip/hip_runtime.h>
#include <cstdint>

#define B_SZ 8192
#define T_SZ 2048

// ---- model constants ----
#define C_LTS       0.126f
#define C_LMIN      (0.5f * 0.089f)
#define C_LMAX      (1.6f * 0.089f)
#define C_KT        35.0f
#define C_CT        0.2f
#define C_VMAX_L0   (10.0f * 0.089f)
#define C_AF_INV    4.0f
#define C_FAT_RATE  0.01f
#define C_REC_RATE  0.002f
#define C_TAU_ACT   0.01f
#define C_TAU_DEACT 0.04f
#define C_L0SIN     0.0077598346f          // L0 * sin(0.0873)
#define C_LMT_DEF   0.2146610680f          // LTS + L0*cos(0.0873)
#define C_INV_EM5   0.006783655f           // 1/(e^5 - 1)
#define C_INV_LTS   (1.0f / 0.126f)
#define C_INV_L0    (1.0f / 0.089f)
#define C_NN_SCALE  0.02f                  // (1-PHYSICS_WEIGHT) * 0.1

typedef __attribute__((ext_vector_type(8))) short bf16x8;
typedef __attribute__((ext_vector_type(4))) float f32x4;

__device__ __forceinline__ float fast_tanh(float x) {
    float e2 = __expf(2.0f * x);
    return (e2 - 1.0f) / (e2 + 1.0f);
}
__device__ __forceinline__ float clampf(float x, float lo, float hi) {
    return fminf(fmaxf(x, lo), hi);
}
__device__ __forceinline__ short f2bf_trunc(float f) {
    return (short)(__float_as_uint(f) >> 16);
}
__device__ __forceinline__ short f2bf_rne(float f) {
    uint32_t u = __float_as_uint(f);
    u += 0x7fff + ((u >> 16) & 1);
    return (short)(u >> 16);
}
__device__ __forceinline__ float bf2f(short s) {
    return __uint_as_float(((uint32_t)(unsigned short)s) << 16);
}

// One wave (64 threads) per block; wave owns 16 elements, fully autonomous.
// lane = q*16 + r:  r = element-within-tile (A-operand m / D col-index role),
//                   q = k-octet selector for MFMA fragments.
__global__ __launch_bounds__(64, 1) void ode_kernel(
    const float* __restrict__ init_state,   // (B,3)
    const float* __restrict__ exc,          // (B,T)
    const float* __restrict__ tspan,        // (T,)
    const float* __restrict__ W1,           // (4,64)
    const float* __restrict__ b1,           // (64,)
    const float* __restrict__ W2,           // (64,64)
    const float* __restrict__ b2,           // (64,)
    const float* __restrict__ W3,           // (64,3)
    const float* __restrict__ b3,           // (3,)
    float* __restrict__ out)                // (T,B,3)
{
    const int lane = threadIdx.x;
    const int r = lane & 15;
    const int q = lane >> 4;
    const int el = (blockIdx.x << 4) + r;   // global element this lane serves

    // ---------------- one-time weight preload (registers only) ----------------
    // Layer-1 weights for this lane's 16 fragment j-slots: j(u) = (u>>3)*32 + q*8 + (u&7)
    float w1r0[16], w1r1[16], w1r2[16], w1r3[16], b1r[16];
    #pragma unroll
    for (int u = 0; u < 16; ++u) {
        const int j = ((u >> 3) << 5) + (q << 3) + (u & 7);
        b1r[u]  = b1[j];
        w1r0[u] = W1[j];
        w1r1[u] = W1[64 + j];
        w1r2[u] = W1[128 + j];
        w1r3[u] = W1[192 + j];
    }
    // W2 as bf16 B-fragments, hi/lo split. B[k][n]: n = ct*16 + r, k = ks*32 + q*8 + t.
    bf16x8 Bh[4][2], Bl[4][2];
    #pragma unroll
    for (int ct = 0; ct < 4; ++ct)
        #pragma unroll
        for (int ks = 0; ks < 2; ++ks)
            #pragma unroll
            for (int t = 0; t < 8; ++t) {
                const int k   = (ks << 5) + (q << 3) + t;
                const int col = (ct << 4) + r;
                const float w = W2[k * 64 + col];
                const short hi = f2bf_trunc(w);
                Bh[ct][ks][t] = hi;
                Bl[ct][ks][t] = f2bf_rne(w - bf2f(hi));
            }
    // Layer-3 weights + biases for this lane's col = ct*16 + r
    float w3r[4][3], b2v[4];
    #pragma unroll
    for (int ct = 0; ct < 4; ++ct) {
        const int col = (ct << 4) + r;
        b2v[ct] = b2[col];
        w3r[ct][0] = W3[col * 3 + 0];
        w3r[ct][1] = W3[col * 3 + 1];
        w3r[ct][2] = W3[col * 3 + 2];
    }
    const float b3v0 = b3[0], b3v1 = b3[1], b3v2 = b3[2];

    // ---------------- state (replicated across the 4 q-copies of el) ----------------
    float yb0 = init_state[el * 3 + 0];
    float yb1 = init_state[el * 3 + 1];
    float yb2 = init_state[el * 3 + 2];
    float cs0 = yb0, cs1 = yb1, cs2 = yb2;   // current stage state (raw)
    float ka0 = 0.f, ka1 = 0.f, ka2 = 0.f;   // k1 + 2k2 + 2k3 accumulator

    if (q == 0) {
        out[(size_t)el * 3 + 0] = yb0;
        out[(size_t)el * 3 + 1] = yb1;
        out[(size_t)el * 3 + 2] = yb2;
    }

    float excA = exc[(size_t)el * T_SZ];     // k1 column for step 0
    float t0 = tspan[0];

    #pragma unroll 1
    for (int i = 0; i < T_SZ - 1; ++i) {
        const float t1 = tspan[i + 1];
        const float dt = t1 - t0;
        const float excB = exc[(size_t)el * T_SZ + i];   // k2..k4 column

        #pragma unroll 1
        for (int ev = 0; ev < 4; ++ev) {
            const float excv = (ev == 0) ? excA : excB;
            const float s0 = cs0, s1 = cs1, s2 = cs2;

            // ---- layer 1 directly into A-fragment slots ----
            float h1v[16];
            #pragma unroll
            for (int u = 0; u < 16; ++u) {
                float pre = b1r[u];
                pre = fmaf(s0,   w1r0[u], pre);
                pre = fmaf(s1,   w1r1[u], pre);
                pre = fmaf(s2,   w1r2[u], pre);
                pre = fmaf(excv, w1r3[u], pre);
                h1v[u] = fast_tanh(pre);
            }
            bf16x8 Ah[2], Al[2];
            #pragma unroll
            for (int ks = 0; ks < 2; ++ks)
                #pragma unroll
                for (int t = 0; t < 8; ++t) {
                    const float h = h1v[(ks << 3) + t];
                    const short hi = f2bf_trunc(h);
                    Ah[ks][t] = hi;
                    Al[ks][t] = f2bf_rne(h - bf2f(hi));
                }

            // ---- layer 2: 16el x 64col GEMV via MFMA, hi/lo split (drop lo*lo) ----
            f32x4 acc[4];
            #pragma unroll
            for (int ct = 0; ct < 4; ++ct) {
                const float bb = b2v[ct];
                acc[ct] = (f32x4){bb, bb, bb, bb};
            }
            #pragma unroll
            for (int ct = 0; ct < 4; ++ct)
                #pragma unroll
                for (int ks = 0; ks < 2; ++ks) {
                    acc[ct] = __builtin_amdgcn_mfma_f32_16x16x32_bf16(Al[ks], Bh[ct][ks], acc[ct], 0, 0, 0);
                    acc[ct] = __builtin_amdgcn_mfma_f32_16x16x32_bf16(Ah[ks], Bl[ct][ks], acc[ct], 0, 0, 0);
                    acc[ct] = __builtin_amdgcn_mfma_f32_16x16x32_bf16(Ah[ks], Bh[ct][ks], acc[ct], 0, 0, 0);
                }

            // ---- layer 2 tanh + layer 3 partials (lane's col = ct*16+r, rows = q*4+reg) ----
            float p[12];   // p[c*4+reg]
            #pragma unroll
            for (int v = 0; v < 12; ++v) p[v] = 0.f;
            #pragma unroll
            for (int ct = 0; ct < 4; ++ct)
                #pragma unroll
                for (int reg = 0; reg < 4; ++reg) {
                    const float h2 = fast_tanh(acc[ct][reg]);
                    p[0 + reg] = fmaf(h2, w3r[ct][0], p[0 + reg]);
                    p[4 + reg] = fmaf(h2, w3r[ct][1], p[4 + reg]);
                    p[8 + reg] = fmaf(h2, w3r[ct][2], p[8 + reg]);
                }

            // ---- reduce over the 16 cols held across r-lanes (butterfly allreduce) ----
            #pragma unroll
            for (int v = 0; v < 12; ++v) {
                #pragma unroll
                for (int m = 1; m < 16; m <<= 1)
                    p[v] += __shfl_xor(p[v], m, 64);
            }

            // ---- fetch this lane's element sums: el=r lives at quad r>>2, reg r&3 ----
            const int src = ((r >> 2) << 4) + r;
            float S0 = 0.f, S1 = 0.f, S2 = 0.f;
            #pragma unroll
            for (int rg = 0; rg < 4; ++rg) {
                const float a0 = __shfl(p[0 + rg], src, 64);
                const float a1 = __shfl(p[4 + rg], src, 64);
                const float a2 = __shfl(p[8 + rg], src, 64);
                if (rg == (r & 3)) { S0 = a0; S1 = a1; S2 = a2; }
            }

            const float nn0 = C_NN_SCALE * fast_tanh(S0 + b3v0);
            const float nn1 = C_NN_SCALE * fast_tanh(S1 + b3v1);
            const float nn2 = C_NN_SCALE * fast_tanh(S2 + b3v2);

            // ---- physics on raw stage state (replicated per lane, el = r) ----
            const float lM  = clampf(s0, C_LMIN, C_LMAX);
            const float act = clampf(s1, 0.01f, 1.0f);
            const float fat = clampf(s2, 0.0f, 1.0f);
            const float a_eff = act * (1.0f - fat);
            const float sin_p = clampf(C_L0SIN / lM, 0.0f, 0.99f);
            const float cos_p = sqrtf(1.0f - sin_p * sin_p);
            const float lT   = C_LMT_DEF - lM * cos_p;
            const float epsT = (lT - C_LTS) * C_INV_LTS;
            const float fT   = (epsT > 0.0f) ? C_CT * (__expf(C_KT * epsT) - 1.0f) : 0.0f;
            const float lN   = lM * C_INV_L0;
            const float d1   = lN - 1.0f;
            const float fL   = __expf(-d1 * d1 * (1.0f / 0.45f));
            const float fPE  = (lN > 1.0f) ? (__expf(8.3333333333f * d1) - 1.0f) * C_INV_EM5 : 0.0f;
            const float fV   = (fT / cos_p - fPE) / (a_eff * fL + 0.001f);
            float vN = (fV - 1.0f) / (1.0f + fabsf(fV) * C_AF_INV);
            vN = clampf(vN, -1.0f, 1.5f);
            const float r0 = C_VMAX_L0 * vN + nn0;
            const float tau = (excv > act) ? C_TAU_ACT * (0.5f + 1.5f * act)
                                           : C_TAU_DEACT / (0.5f + 1.5f * act);
            const float r1 = (excv - act) / tau + nn1;
            const float r2 = C_FAT_RATE * a_eff * (1.0f - fat)
                           - C_REC_RATE * (1.0f - a_eff) * fat + nn2;

            // ---- RK4 bookkeeping (replicated; identical across q-copies) ----
            if (ev == 0) {
                ka0 = r0; ka1 = r1; ka2 = r2;
                cs0 = fmaf(0.5f * dt, r0, yb0); cs1 = fmaf(0.5f * dt, r1, yb1); cs2 = fmaf(0.5f * dt, r2, yb2);
            } else if (ev == 1) {
                ka0 = fmaf(2.0f, r0, ka0); ka1 = fmaf(2.0f, r1, ka1); ka2 = fmaf(2.0f, r2, ka2);
                cs0 = fmaf(0.5f * dt, r0, yb0); cs1 = fmaf(0.5f * dt, r1, yb1); cs2 = fmaf(0.5f * dt, r2, yb2);
            } else if (ev == 2) {
                ka0 = fmaf(2.0f, r0, ka0); ka1 = fmaf(2.0f, r1, ka1); ka2 = fmaf(2.0f, r2, ka2);
                cs0 = fmaf(dt, r0, yb0); cs1 = fmaf(dt, r1, yb1); cs2 = fmaf(dt, r2, yb2);
            } else {
                const float c = dt * (1.0f / 6.0f);
                yb0 = fmaf(c, ka0 + r0, yb0);
                yb1 = fmaf(c, ka1 + r1, yb1);
                yb2 = fmaf(c, ka2 + r2, yb2);
                cs0 = yb0; cs1 = yb1; cs2 = yb2;
                if (q == 0) {
                    const size_t ob = (size_t)(i + 1) * (B_SZ * 3) + (size_t)el * 3;
                    out[ob + 0] = yb0; out[ob + 1] = yb1; out[ob + 2] = yb2;
                }
            }
        }

        excA = excB;
        t0 = t1;
    }
}

extern "C" void kernel_launch(void* const* d_in, const int* in_sizes, int n_in,
                              void* d_out, int out_size, void* d_ws, size_t ws_size,
                              hipStream_t stream) {
    const float* init  = (const float*)d_in[0];
    const float* exc   = (const float*)d_in[1];
    const float* tspan = (const float*)d_in[2];
    const float* W1    = (const float*)d_in[3];
    const float* b1    = (const float*)d_in[4];
    const float* W2    = (const float*)d_in[5];
    const float* b2    = (const float*)d_in[6];
    const float* W3    = (const float*)d_in[7];
    const float* b3    = (const float*)d_in[8];

    hipLaunchKernelGGL(ode_kernel, dim3(B_SZ / 16), dim3(64), 0, stream,
                       init, exc, tspan, W1, b1, W2, b2, W3, b3, (float*)d_out);
}